// Round 5
// baseline (1700.053 us; speedup 1.0000x reference)
//
#include <hip/hip_runtime.h>

#define KCODES 1024
#define DDIM 128
#define HW 64
#define NPIX (32 * HW * HW)         // 131072 pixels
#define PLANE (HW * HW)             // 4096
#define BSTRIDE (DDIM * PLANE)      // 524288 floats per batch image
#define CAP_A 65536
// phase1 computes 1024*(Bsum_k - 2 z.c) with single fp16 MFMA (codebook
// pre-scaled by exactly 1024 so all values are fp16-normal; scaling is a
// pow2 -> error-free). Worst-case phase1 error ~1.3e-4 (unscaled) + ref
// fp32 band 3.2e-5 -> MARGIN 4e-4 (scaled: 0.4096). All flagged pixels go
// to an exact full-scan resolve (numpy-semantics fp64 dot + lex tie-break).
#define MARGIN_SC 0.4096f
#define BAND 1e-4f                  // phase3 fp32-prefilter band (unscaled)

typedef __attribute__((ext_vector_type(8)))  _Float16 f16x8;  // MFMA A/B frag
typedef __attribute__((ext_vector_type(4)))  float    f32x4;
typedef __attribute__((ext_vector_type(16))) float    f32x16; // 32x32 C/D

// async global->LDS, 16B per lane (wave-uniform LDS base; HW adds lane*16)
__device__ inline void gll16(const void* g, void* l) {
    __builtin_amdgcn_global_load_lds(
        (const __attribute__((address_space(1))) unsigned int*)g,
        (__attribute__((address_space(3))) unsigned int*)l, 16, 0, 0);
}

// ---------------------------------------------------------------------------
// prep: blocks 0..3  -> Bsum[k] (numpy-pairwise, contract off) + 1024*Bsum
//       blocks 4..67 -> codebook*1024 as fp16 in 32x32x16 MFMA B-frag order
// frag layout: half off = ((c*8+s)*64 + l)*8 + j   (c=tile of 32 codes,
// s=kchunk of 16; lane l holds B[k=s*16+(l>>5)*8+j][n=c*32+(l&31)]).
// block 0 thread 0 also zeroes cntA (prep completes before phase1).
// ---------------------------------------------------------------------------
__global__ __launch_bounds__(256) void prep_kernel(const float* __restrict__ cb,
                                                   float* __restrict__ Bsum,
                                                   float* __restrict__ Bs1024,
                                                   _Float16* __restrict__ bs16,
                                                   int* __restrict__ cntA) {
    int bid = blockIdx.x;
    if (bid < 4) {
        if (bid == 0 && threadIdx.x == 0) *cntA = 0;
        {
#pragma clang fp contract(off)
            int k = bid * 256 + threadIdx.x;
            const float* row = cb + k * DDIM;
            float r0,r1,r2,r3,r4,r5,r6,r7;
            r0 = row[0]*row[0]; r1 = row[1]*row[1]; r2 = row[2]*row[2]; r3 = row[3]*row[3];
            r4 = row[4]*row[4]; r5 = row[5]*row[5]; r6 = row[6]*row[6]; r7 = row[7]*row[7];
#pragma unroll
            for (int i = 8; i < DDIM; i += 8) {
                r0 += row[i+0]*row[i+0]; r1 += row[i+1]*row[i+1];
                r2 += row[i+2]*row[i+2]; r3 += row[i+3]*row[i+3];
                r4 += row[i+4]*row[i+4]; r5 += row[i+5]*row[i+5];
                r6 += row[i+6]*row[i+6]; r7 += row[i+7]*row[i+7];
            }
            float bs = ((r0+r1)+(r2+r3)) + ((r4+r5)+(r6+r7));
            Bsum[k] = bs;
            Bs1024[k] = 1024.0f * bs;          // pow2 scale: exact
        }
    } else {
        int t = (bid - 4) * 256 + threadIdx.x; // 16384 = 32c * 8s * 64l
        int c = t >> 9, s = (t >> 6) & 7, l = t & 63;
        int n = l & 31, half = l >> 5;
        int code = c * 32 + n;
        int d0 = s * 16 + half * 8;
        const float* row = cb + code * DDIM + d0;
        f32x4 f0 = *(const f32x4*)(row);
        f32x4 f1 = *(const f32x4*)(row + 4);
        f16x8 v;
#pragma unroll
        for (int e = 0; e < 4; ++e) {
            v[e]     = (_Float16)(1024.0f * f0[e]);   // RNE cvt
            v[4 + e] = (_Float16)(1024.0f * f1[e]);
        }
        *(f16x8*)(bs16 + ((size_t)((c * 8 + s) * 64 + l)) * 8) = v;
    }
}

// ---------------------------------------------------------------------------
// phase1: single-fp16 32x32x16 MFMA distance (scaled by 1024) + top-2 argmin.
// Block = 4 waves = 128 px; each wave owns 32 contiguous w of one h row.
// B: two 8KB tiles (2x32 codes) per LDS buffer, double-buffered (2x16KB),
// staged with global_load_lds dwordx4; ONE barrier per 2 tiles (16 total).
// acc init = 1024*Bsum[k] (from LDS) -> MFMA output IS the scaled distance.
// Tracking per row: m2=min(m2,max(m1,d)); m1=min(m1,d); i1 cndmask (5 VALU).
// C/D: col(code)=lane&31, row(pixel)=(r&3)+8*(r>>2)+4*(lane>>5).
// ---------------------------------------------------------------------------
__global__ __launch_bounds__(256, 3) void phase1_mfma(
    const float* __restrict__ z, const float* __restrict__ cb,
    const _Float16* __restrict__ bs16, const float* __restrict__ Bs1024,
    float* __restrict__ out, int* __restrict__ cntA, int* __restrict__ listA)
{
    __shared__ __align__(16) _Float16 btile[2][8192];   // 2 x 16KB
    __shared__ float bsumLds[1024];
    __shared__ int idxb[128];
    const int tid = threadIdx.x;
    const int lane = tid & 63, wv = tid >> 6;
    const int wg = blockIdx.x;                 // 1024 blocks
    const int b = wg >> 5;
    const int h = (wg & 31) * 2 + (wv >> 1);
    const int w0 = (wv & 1) * 32;
    const int col = lane & 31, half = lane >> 5;

    // stage scaled Bsum into LDS (1024 f32, vectorized)
    *(f32x4*)(bsumLds + tid * 4) = *(const f32x4*)(Bs1024 + tid * 4);

    // A fragments: pixel m=col -> w=w0+col; chunk s covers d=s*16+half*8+e
    const float* zbase = z + (size_t)b * BSTRIDE + h * HW + w0 + col;
    f16x8 za[8];
#pragma unroll
    for (int s = 0; s < 8; ++s) {
        const float* zp = zbase + (size_t)(s * 16 + half * 8) * PLANE;
        f16x8 a;
#pragma unroll
        for (int e = 0; e < 8; ++e)
            a[e] = (_Float16)(-2.0f * zp[(size_t)e * PLANE]);
        za[s] = a;
    }

    float m1[16], m2[16]; int i1[16];
#pragma unroll
    for (int r = 0; r < 16; ++r) { m1[r] = 3.4e38f; m2[r] = 3.4e38f; i1[r] = 0; }

    // staging: wave wv owns bytes [wv*4096, +4096) of each 16KB buffer
    const char* bb = (const char*)bs16;
#define STAGE(BUF, P) do {                                                   \
        const char* s_ = bb + (size_t)(P) * 16384 + wv * 4096 + lane * 16;   \
        char* d_ = (char*)&btile[BUF][0] + wv * 4096;                        \
        gll16(s_,        d_);                                                \
        gll16(s_ + 1024, d_ + 1024);                                         \
        gll16(s_ + 2048, d_ + 2048);                                         \
        gll16(s_ + 3072, d_ + 3072);                                         \
    } while (0)

    STAGE(0, 0);
    __syncthreads();

    for (int j = 0; j < 16; ++j) {             // 2 code-tiles per iteration
        const int cur = j & 1;
        if (j < 15) STAGE(cur ^ 1, j + 1);     // prefetch next 16KB
        const f16x8* bf = (const f16x8*)btile[cur];
#pragma unroll
        for (int t = 0; t < 2; ++t) {
            int kcol = (j * 2 + t) * 32 + col;
            float bsv = bsumLds[kcol];         // broadcast ds_read_b32
            f32x16 acc;
#pragma unroll
            for (int r = 0; r < 16; ++r) acc[r] = bsv;
#pragma unroll
            for (int s = 0; s < 8; ++s) {
                f16x8 bh = bf[(t * 8 + s) * 64 + lane];
                acc = __builtin_amdgcn_mfma_f32_32x32x16_f16(za[s], bh, acc, 0, 0, 0);
            }
#pragma unroll
            for (int r = 0; r < 16; ++r) {
                float dv = acc[r];
                float mx = fmaxf(m1[r], dv);
                m2[r] = fminf(m2[r], mx);
                bool lt = dv < m1[r];
                i1[r] = lt ? kcol : i1[r];     // strict < keeps lowest index
                m1[r] = fminf(m1[r], dv);
            }
        }
        __syncthreads();                       // reads done + prefetch landed
    }
#undef STAGE

    // merge (m1,i1,m2) across the 32 lanes (code columns) per row set
#pragma unroll
    for (int mask = 1; mask <= 16; mask <<= 1) {
#pragma unroll
        for (int r = 0; r < 16; ++r) {
            float b1 = __shfl_xor(m1[r], mask, 64);
            float b2 = __shfl_xor(m2[r], mask, 64);
            int  ib1 = __shfl_xor(i1[r], mask, 64);
            float a1 = m1[r]; int ia1 = i1[r];
            bool bl = (b1 < a1) || (b1 == a1 && ib1 < ia1);
            float mx = fmaxf(a1, b1);                   // loser of firsts
            m2[r] = fminf(fminf(m2[r], b2), mx);        // global 2nd (value)
            m1[r] = bl ? b1 : a1;
            i1[r] = bl ? ib1 : ia1;
        }
    }

    if (col == 0) {                  // 2 writer lanes per wave (half=0/1)
#pragma unroll
        for (int r = 0; r < 16; ++r) {
            int row = (r & 3) + 8 * (r >> 2) + 4 * half;
            idxb[wv * 32 + row] = i1[r];
            if (m2[r] - m1[r] <= MARGIN_SC) {           // ambiguous -> exact
                int pix = (b * 64 + h) * 64 + w0 + row;
                int pos = atomicAdd(cntA, 1);
                if (pos < CAP_A) listA[pos] = pix;
            }
        }
    }
    __syncthreads();

    // write guess: lane -> pixel w = w0+col; half selects d in [half*64,+64)
    int widx = idxb[wv * 32 + col];
    const float* crow = cb + widx * DDIM + half * 64;
    float* ob = out + (size_t)b * BSTRIDE + (size_t)(half * 64) * PLANE
              + h * HW + w0 + col;
#pragma unroll
    for (int dd = 0; dd < 16; ++dd) {
        f32x4 c4 = *(const f32x4*)(crow + dd * 4);
        ob[(size_t)(dd * 4 + 0) * PLANE] = c4[0];
        ob[(size_t)(dd * 4 + 1) * PLANE] = c4[1];
        ob[(size_t)(dd * 4 + 2) * PLANE] = c4[2];
        ob[(size_t)(dd * 4 + 3) * PLANE] = c4[3];
    }
}

// ---------------------------------------------------------------------------
// phase3: exact full-scan resolve for flagged pixels. One wave per item.
//   fp32 prefilter over all 1024 codes (16/lane), candidates within
//   smin+BAND get the exact path:
//     A   = numpy-pairwise sum of z^2 (fp32, contract off)
//     p   = fp64 dot;  D_k = fl32( fl32(A+Bsum_k) - fl32(2p) )
//   winner = lex min (D, k). Matches reference fp32 semantics.
// ---------------------------------------------------------------------------
__global__ __launch_bounds__(256, 4) void phase3_kernel(
    const float* __restrict__ z, const float* __restrict__ cb,
    const float* __restrict__ Bsum, float* __restrict__ out,
    const int* __restrict__ cntA, const int* __restrict__ listA)
{
    __shared__ float zsh[4][128];
    const int tid = threadIdx.x, lane = tid & 63, wv = tid >> 6;
    int gwave = (blockIdx.x * 256 + tid) >> 6;
    int nwaves = gridDim.x * 4;
    int nitems = *cntA; if (nitems > CAP_A) nitems = CAP_A;

    for (int item = gwave; item < nitems; item += nwaves) {
        int pix = listA[item];
        int b = pix >> 12, h = (pix >> 6) & 63, w = pix & 63;
        const float* zp = z + (size_t)b * BSTRIDE + h * HW + w;

        float za = zp[(size_t)lane * PLANE];
        float zb = zp[(size_t)(lane + 64) * PLANE];
        zsh[wv][lane] = za;                    // wave-internal: in-order LDS
        zsh[wv][lane + 64] = zb;
        const float* zr = zsh[wv];

        // numpy pairwise A (redundant per lane; contract off)
        float Apair;
        {
#pragma clang fp contract(off)
            float r0,r1,r2,r3,r4,r5,r6,r7;
            r0 = zr[0]*zr[0]; r1 = zr[1]*zr[1]; r2 = zr[2]*zr[2]; r3 = zr[3]*zr[3];
            r4 = zr[4]*zr[4]; r5 = zr[5]*zr[5]; r6 = zr[6]*zr[6]; r7 = zr[7]*zr[7];
#pragma unroll
            for (int i = 8; i < DDIM; i += 8) {
                r0 += zr[i+0]*zr[i+0]; r1 += zr[i+1]*zr[i+1];
                r2 += zr[i+2]*zr[i+2]; r3 += zr[i+3]*zr[i+3];
                r4 += zr[i+4]*zr[i+4]; r5 += zr[i+5]*zr[i+5];
                r6 += zr[i+6]*zr[i+6]; r7 += zr[i+7]*zr[i+7];
            }
            Apair = ((r0+r1)+(r2+r3)) + ((r4+r5)+(r6+r7));
        }

        // fp32 prefilter: lane owns codes k = g*64+lane, g=0..15
        float dot[16];
#pragma unroll
        for (int g = 0; g < 16; ++g) dot[g] = 0.0f;
        for (int i = 0; i < 32; ++i) {
            f32x4 zv = *(const f32x4*)(zr + i * 4);   // broadcast LDS read
#pragma unroll
            for (int g = 0; g < 16; ++g) {
                const f32x4 cv = *(const f32x4*)(cb + (size_t)(g * 64 + lane) * DDIM + i * 4);
                dot[g] = __builtin_fmaf(zv[0], cv[0],
                         __builtin_fmaf(zv[1], cv[1],
                         __builtin_fmaf(zv[2], cv[2],
                         __builtin_fmaf(zv[3], cv[3], dot[g]))));
            }
        }
        float est[16]; float smin = 3.4e38f;
#pragma unroll
        for (int g = 0; g < 16; ++g) {
            est[g] = Bsum[g * 64 + lane] - 2.0f * dot[g];
            smin = fminf(smin, est[g]);
        }
        for (int off = 32; off; off >>= 1)
            smin = fminf(smin, __shfl_xor(smin, off, 64));

        // exact path for candidates
        float bd = 3.4e38f; int bk = 1 << 30;
#pragma unroll 1
        for (int g = 0; g < 16; ++g) {
            if (est[g] <= smin + BAND) {
                int k = g * 64 + lane;
                const float* c = cb + (size_t)k * DDIM;
                double p = 0.0;
                for (int i = 0; i < DDIM; ++i)
                    p = fma((double)zr[i], (double)c[i], p);
                float Dk;
                {
#pragma clang fp contract(off)
                    float t1 = Apair + Bsum[k];
                    float u = (float)(2.0 * p);
                    Dk = t1 - u;
                }
                if (Dk < bd || (Dk == bd && k < bk)) { bd = Dk; bk = k; }
            }
        }
        for (int off = 32; off; off >>= 1) {
            float od = __shfl_xor(bd, off, 64);
            int   ok = __shfl_xor(bk, off, 64);
            bool better = (od < bd) || (od == bd && ok < bk);
            bd = better ? od : bd;
            bk = better ? ok : bk;
        }

        const float* cw = cb + (size_t)bk * DDIM;
        float* op = out + (size_t)b * BSTRIDE + h * HW + w;
        op[(size_t)lane * PLANE] = cw[lane];
        op[(size_t)(lane + 64) * PLANE] = cw[lane + 64];
    }
}

// ---------------------------------------------------------------------------
extern "C" void kernel_launch(void* const* d_in, const int* in_sizes, int n_in,
                              void* d_out, int out_size, void* d_ws, size_t ws_size,
                              hipStream_t stream) {
    const float* z  = (const float*)d_in[0];
    const float* cb = (const float*)d_in[1];
    float* out = (float*)d_out;

    // ws: Bsum 4K | Bs1024 4K | cntA 4K | bs16 256K | listA 256K
    float* Bsum   = (float*)d_ws;
    float* Bs1024 = (float*)((char*)d_ws + 4096);
    int*   cntA   = (int*)((char*)d_ws + 8192);
    _Float16* bs16 = (_Float16*)((char*)d_ws + 12288);
    int*   listA  = (int*)((char*)d_ws + 12288 + 262144);

    prep_kernel<<<68, 256, 0, stream>>>(cb, Bsum, Bs1024, bs16, cntA);
    phase1_mfma<<<NPIX / 128, 256, 0, stream>>>(z, cb, bs16, Bs1024, out,
                                                cntA, listA);
    phase3_kernel<<<512, 256, 0, stream>>>(z, cb, Bsum, out, cntA, listA);
}

// Round 6
// 663.529 us; speedup vs baseline: 2.5621x; 2.5621x over previous
//
#include <hip/hip_runtime.h>

#define KCODES 1024
#define DDIM 128
#define HW 64
#define NPIX (32 * HW * HW)         // 131072 pixels
#define PLANE (HW * HW)             // 4096
#define BSTRIDE (DDIM * PLANE)      // 524288 floats per batch image
#define CAP_A 65536
#define CAP_B 8192
// phase1 computes 1024*(Bsum_k - 2 z.c) with single fp16 MFMA (codebook
// pre-scaled by exactly 1024 so all values are fp16-normal; pow2 scale is
// error-free). Per-code error RMS ~0.015 scaled; MARGIN_SC = 0.4096 ~ 19
// sigma (+ covers ref fp32 band 3.2e-5*1024=0.033). Flagged pixels:
// 2 candidates -> exact fp64 2-way resolve; >=3 candidates -> full scan.
#define MARGIN_SC 0.4096f
#define BAND 1e-4f                  // phase3b fp32-prefilter band (unscaled)

typedef __attribute__((ext_vector_type(8)))  _Float16 f16x8;  // MFMA A/B frag
typedef __attribute__((ext_vector_type(4)))  float    f32x4;
typedef __attribute__((ext_vector_type(16))) float    f32x16; // 32x32 C/D

// async global->LDS, 16B per lane (wave-uniform LDS base; HW adds lane*16)
__device__ inline void gll16(const void* g, void* l) {
    __builtin_amdgcn_global_load_lds(
        (const __attribute__((address_space(1))) unsigned int*)g,
        (__attribute__((address_space(3))) unsigned int*)l, 16, 0, 0);
}

// ---------------------------------------------------------------------------
// prep: blocks 0..3  -> Bsum[k] (numpy-pairwise, contract off) + 1024*Bsum
//       blocks 4..67 -> codebook*1024 as fp16 in 32x32x16 MFMA B-frag order
// frag layout: half off = ((c*8+s)*64 + l)*8 + j   (c=tile of 32 codes,
// s=kchunk of 16; lane l holds B[k=s*16+(l>>5)*8+j][n=c*32+(l&31)]).
// block 0 thread 0 also zeroes cntA/cntB (prep completes before phase1).
// ---------------------------------------------------------------------------
__global__ __launch_bounds__(256) void prep_kernel(const float* __restrict__ cb,
                                                   float* __restrict__ Bsum,
                                                   float* __restrict__ Bs1024,
                                                   _Float16* __restrict__ bs16,
                                                   int* __restrict__ cnts) {
    int bid = blockIdx.x;
    if (bid < 4) {
        if (bid == 0 && threadIdx.x == 0) { cnts[0] = 0; cnts[1] = 0; }
        {
#pragma clang fp contract(off)
            int k = bid * 256 + threadIdx.x;
            const float* row = cb + k * DDIM;
            float r0,r1,r2,r3,r4,r5,r6,r7;
            r0 = row[0]*row[0]; r1 = row[1]*row[1]; r2 = row[2]*row[2]; r3 = row[3]*row[3];
            r4 = row[4]*row[4]; r5 = row[5]*row[5]; r6 = row[6]*row[6]; r7 = row[7]*row[7];
#pragma unroll
            for (int i = 8; i < DDIM; i += 8) {
                r0 += row[i+0]*row[i+0]; r1 += row[i+1]*row[i+1];
                r2 += row[i+2]*row[i+2]; r3 += row[i+3]*row[i+3];
                r4 += row[i+4]*row[i+4]; r5 += row[i+5]*row[i+5];
                r6 += row[i+6]*row[i+6]; r7 += row[i+7]*row[i+7];
            }
            float bs = ((r0+r1)+(r2+r3)) + ((r4+r5)+(r6+r7));
            Bsum[k] = bs;
            Bs1024[k] = 1024.0f * bs;          // pow2 scale: exact
        }
    } else {
        int t = (bid - 4) * 256 + threadIdx.x; // 16384 = 32c * 8s * 64l
        int c = t >> 9, s = (t >> 6) & 7, l = t & 63;
        int n = l & 31, half = l >> 5;
        int code = c * 32 + n;
        int d0 = s * 16 + half * 8;
        const float* row = cb + code * DDIM + d0;
        f32x4 f0 = *(const f32x4*)(row);
        f32x4 f1 = *(const f32x4*)(row + 4);
        f16x8 v;
#pragma unroll
        for (int e = 0; e < 4; ++e) {
            v[e]     = (_Float16)(1024.0f * f0[e]);   // RNE cvt
            v[4 + e] = (_Float16)(1024.0f * f1[e]);
        }
        *(f16x8*)(bs16 + ((size_t)((c * 8 + s) * 64 + l)) * 8) = v;
    }
}

// ---------------------------------------------------------------------------
// phase1: single-fp16 32x32x16 MFMA distance (scaled by 1024) + top-3 argmin.
// Block = 4 waves = 128 px; each wave owns 32 contiguous w of one h row.
// B: two 8KB tiles (2x32 codes) per LDS buffer, double-buffered (2x16KB),
// staged with global_load_lds dwordx4; ONE barrier per 2 tiles (16 total).
// acc init = 1024*Bsum[k] (from LDS) -> MFMA output IS the scaled distance.
// Tracks (m1,i1,m2,i2,m3): m2-m1<=MARGIN -> listA{pix,k1,k2};
// additionally m3-m1<=MARGIN -> listB{pix} (full-scan fallback, rare).
// C/D: col(code)=lane&31, row(pixel)=(r&3)+8*(r>>2)+4*(lane>>5).
// ---------------------------------------------------------------------------
__global__ __launch_bounds__(256, 3) void phase1_mfma(
    const float* __restrict__ z, const float* __restrict__ cb,
    const _Float16* __restrict__ bs16, const float* __restrict__ Bs1024,
    float* __restrict__ out, int* __restrict__ cntA, int2* __restrict__ listA,
    int* __restrict__ cntB, int* __restrict__ listB)
{
    __shared__ __align__(16) _Float16 btile[2][8192];   // 2 x 16KB
    __shared__ float bsumLds[1024];
    __shared__ int idxb[128];
    const int tid = threadIdx.x;
    const int lane = tid & 63, wv = tid >> 6;
    const int wg = blockIdx.x;                 // 1024 blocks
    const int b = wg >> 5;
    const int h = (wg & 31) * 2 + (wv >> 1);
    const int w0 = (wv & 1) * 32;
    const int col = lane & 31, half = lane >> 5;

    // stage scaled Bsum into LDS (1024 f32, vectorized)
    *(f32x4*)(bsumLds + tid * 4) = *(const f32x4*)(Bs1024 + tid * 4);

    // A fragments: pixel m=col -> w=w0+col; chunk s covers d=s*16+half*8+e
    const float* zbase = z + (size_t)b * BSTRIDE + h * HW + w0 + col;
    f16x8 za[8];
#pragma unroll
    for (int s = 0; s < 8; ++s) {
        const float* zp = zbase + (size_t)(s * 16 + half * 8) * PLANE;
        f16x8 a;
#pragma unroll
        for (int e = 0; e < 8; ++e)
            a[e] = (_Float16)(-2.0f * zp[(size_t)e * PLANE]);
        za[s] = a;
    }

    float m1[16], m2[16], m3[16]; int i1[16], i2[16];
#pragma unroll
    for (int r = 0; r < 16; ++r) {
        m1[r] = 3.4e38f; m2[r] = 3.4e38f; m3[r] = 3.4e38f; i1[r] = 0; i2[r] = 0;
    }

    // staging: wave wv owns bytes [wv*4096, +4096) of each 16KB buffer
    const char* bb = (const char*)bs16;
#define STAGE(BUF, P) do {                                                   \
        const char* s_ = bb + (size_t)(P) * 16384 + wv * 4096 + lane * 16;   \
        char* d_ = (char*)&btile[BUF][0] + wv * 4096;                        \
        gll16(s_,        d_);                                                \
        gll16(s_ + 1024, d_ + 1024);                                         \
        gll16(s_ + 2048, d_ + 2048);                                         \
        gll16(s_ + 3072, d_ + 3072);                                         \
    } while (0)

    STAGE(0, 0);
    __syncthreads();

    for (int j = 0; j < 16; ++j) {             // 2 code-tiles per iteration
        const int cur = j & 1;
        if (j < 15) STAGE(cur ^ 1, j + 1);     // prefetch next 16KB
        const f16x8* bf = (const f16x8*)btile[cur];
#pragma unroll
        for (int t = 0; t < 2; ++t) {
            int kcol = (j * 2 + t) * 32 + col;
            float bsv = bsumLds[kcol];         // broadcast ds_read_b32
            f32x16 acc;
#pragma unroll
            for (int r = 0; r < 16; ++r) acc[r] = bsv;
#pragma unroll
            for (int s = 0; s < 8; ++s) {
                f16x8 bh = bf[(t * 8 + s) * 64 + lane];
                acc = __builtin_amdgcn_mfma_f32_32x32x16_f16(za[s], bh, acc, 0, 0, 0);
            }
            // top-3 values + top-2 indices (9 VALU/row)
#pragma unroll
            for (int r = 0; r < 16; ++r) {
                float dv = acc[r];
                bool lt1 = dv < m1[r];
                bool lt2 = dv < m2[r];
                m3[r] = lt2 ? m2[r] : fminf(m3[r], dv);
                m2[r] = lt1 ? m1[r] : (lt2 ? dv : m2[r]);
                i2[r] = lt1 ? i1[r] : (lt2 ? kcol : i2[r]);
                m1[r] = lt1 ? dv : m1[r];
                i1[r] = lt1 ? kcol : i1[r];
            }
        }
        __syncthreads();                       // reads done + prefetch landed
    }
#undef STAGE

    // merge sorted-3 tuples across the 32 lanes (code columns) per row set
#pragma unroll
    for (int mask = 1; mask <= 16; mask <<= 1) {
#pragma unroll
        for (int r = 0; r < 16; ++r) {
            float b1 = __shfl_xor(m1[r], mask, 64);
            float b2 = __shfl_xor(m2[r], mask, 64);
            float b3 = __shfl_xor(m3[r], mask, 64);
            int  ib1 = __shfl_xor(i1[r], mask, 64);
            int  ib2 = __shfl_xor(i2[r], mask, 64);
            float a1 = m1[r], a2 = m2[r], a3 = m3[r];
            int  ia1 = i1[r], ia2 = i2[r];
            bool bfi = (b1 < a1) || (b1 == a1 && ib1 < ia1);
            float x1 = bfi ? b1 : a1;  int xi1 = bfi ? ib1 : ia1;
            float x2 = bfi ? b2 : a2;  int xi2 = bfi ? ib2 : ia2;
            float x3 = bfi ? b3 : a3;
            float y1 = bfi ? a1 : b1;  int yi1 = bfi ? ia1 : ib1;
            float y2 = bfi ? a2 : b2;
            bool ys = (y1 < x2) || (y1 == x2 && yi1 < xi2);
            m1[r] = x1; i1[r] = xi1;
            m2[r] = ys ? y1 : x2;  i2[r] = ys ? yi1 : xi2;
            m3[r] = ys ? fminf(x2, y2) : fminf(x3, y1);
        }
    }

    if (col == 0) {                  // 2 writer lanes per wave (half=0/1)
#pragma unroll
        for (int r = 0; r < 16; ++r) {
            int row = (r & 3) + 8 * (r >> 2) + 4 * half;
            idxb[wv * 32 + row] = i1[r];
            if (m2[r] - m1[r] <= MARGIN_SC) {           // ambiguous
                int pix = (b * 64 + h) * 64 + w0 + row;
                int pos = atomicAdd(cntA, 1);
                if (pos < CAP_A) {
                    int2 rec; rec.x = pix; rec.y = i1[r] | (i2[r] << 16);
                    listA[pos] = rec;
                }
                if (m3[r] - m1[r] <= MARGIN_SC) {       // >=3 cands (rare)
                    int pb = atomicAdd(cntB, 1);
                    if (pb < CAP_B) listB[pb] = pix;
                }
            }
        }
    }
    __syncthreads();

    // write guess: lane -> pixel w = w0+col; half selects d in [half*64,+64)
    int widx = idxb[wv * 32 + col];
    const float* crow = cb + widx * DDIM + half * 64;
    float* ob = out + (size_t)b * BSTRIDE + (size_t)(half * 64) * PLANE
              + h * HW + w0 + col;
#pragma unroll
    for (int dd = 0; dd < 16; ++dd) {
        f32x4 c4 = *(const f32x4*)(crow + dd * 4);
        ob[(size_t)(dd * 4 + 0) * PLANE] = c4[0];
        ob[(size_t)(dd * 4 + 1) * PLANE] = c4[1];
        ob[(size_t)(dd * 4 + 2) * PLANE] = c4[2];
        ob[(size_t)(dd * 4 + 3) * PLANE] = c4[3];
    }
}

// ---------------------------------------------------------------------------
// phase3a: resolve 2-candidate ambiguous pixels. One wave per item.
//   A    = numpy-pairwise sum of z^2 (fp32, contract off)
//   p    = dot in fp64 (lane-split + shuffle reduce; order-agnostic)
//   D_k  = fl32( fl32(A + Bsum_k) - fl32(2*p) );  winner = lex min (D, k)
// No __syncthreads in the item loop (waves diverge); within-wave LDS ops
// are in-order on CDNA so write->read needs no barrier.
// ---------------------------------------------------------------------------
__global__ __launch_bounds__(256, 4) void phase3a_kernel(
    const float* __restrict__ z, const float* __restrict__ cb,
    const float* __restrict__ Bsum, float* __restrict__ out,
    const int* __restrict__ cntA, const int2* __restrict__ listA)
{
    __shared__ float zsh[4][128];
    const int tid = threadIdx.x, lane = tid & 63, wv = tid >> 6;
    int gwave = (blockIdx.x * 256 + tid) >> 6;
    int nwaves = gridDim.x * 4;
    int nitems = *cntA; if (nitems > CAP_A) nitems = CAP_A;

    for (int item = gwave; item < nitems; item += nwaves) {
        int2 rec = listA[item];
        int pix = rec.x;
        int k1 = rec.y & 0xFFFF, k2 = rec.y >> 16;
        int b = pix >> 12, h = (pix >> 6) & 63, w = pix & 63;
        const float* zp = z + (size_t)b * BSTRIDE + h * HW + w;

        float za = zp[(size_t)lane * PLANE];
        float zb = zp[(size_t)(lane + 64) * PLANE];
        zsh[wv][lane] = za;
        zsh[wv][lane + 64] = zb;

        float Apair;
        {
#pragma clang fp contract(off)
            const float* zr = zsh[wv];
            float r0,r1,r2,r3,r4,r5,r6,r7;
            r0 = zr[0]*zr[0]; r1 = zr[1]*zr[1]; r2 = zr[2]*zr[2]; r3 = zr[3]*zr[3];
            r4 = zr[4]*zr[4]; r5 = zr[5]*zr[5]; r6 = zr[6]*zr[6]; r7 = zr[7]*zr[7];
#pragma unroll
            for (int i = 8; i < DDIM; i += 8) {
                r0 += zr[i+0]*zr[i+0]; r1 += zr[i+1]*zr[i+1];
                r2 += zr[i+2]*zr[i+2]; r3 += zr[i+3]*zr[i+3];
                r4 += zr[i+4]*zr[i+4]; r5 += zr[i+5]*zr[i+5];
                r6 += zr[i+6]*zr[i+6]; r7 += zr[i+7]*zr[i+7];
            }
            Apair = ((r0+r1)+(r2+r3)) + ((r4+r5)+(r6+r7));
        }

        const float* c1 = cb + (size_t)k1 * DDIM;
        const float* c2 = cb + (size_t)k2 * DDIM;
        double p1 = fma((double)za, (double)c1[lane],
                        (double)zb * (double)c1[lane + 64]);
        double p2 = fma((double)za, (double)c2[lane],
                        (double)zb * (double)c2[lane + 64]);
        for (int off = 32; off; off >>= 1) {
            p1 += __shfl_xor(p1, off, 64);
            p2 += __shfl_xor(p2, off, 64);
        }
        float u1 = (float)(2.0 * p1), u2 = (float)(2.0 * p2);
        float D1, D2;
        {
#pragma clang fp contract(off)
            float t1 = Apair + Bsum[k1];
            float t2 = Apair + Bsum[k2];
            D1 = t1 - u1; D2 = t2 - u2;
        }
        int wk = (D1 < D2 || (D1 == D2 && k1 < k2)) ? k1 : k2;

        const float* cw = cb + (size_t)wk * DDIM;
        float* op = out + (size_t)b * BSTRIDE + h * HW + w;
        op[(size_t)lane * PLANE] = cw[lane];
        op[(size_t)(lane + 64) * PLANE] = cw[lane + 64];
    }
}

// ---------------------------------------------------------------------------
// phase3b: exact full-scan resolve for >=3-candidate pixels (rare). One wave
// per item; fp32 prefilter over all 1024 codes (16/lane), candidates within
// smin+BAND get the exact fp64 path. Runs AFTER phase3a so its writes win.
// ---------------------------------------------------------------------------
__global__ __launch_bounds__(256, 4) void phase3b_kernel(
    const float* __restrict__ z, const float* __restrict__ cb,
    const float* __restrict__ Bsum, float* __restrict__ out,
    const int* __restrict__ cntB, const int* __restrict__ listB)
{
    __shared__ float zsh[4][128];
    const int tid = threadIdx.x, lane = tid & 63, wv = tid >> 6;
    int gwave = (blockIdx.x * 256 + tid) >> 6;
    int nwaves = gridDim.x * 4;
    int nitems = *cntB; if (nitems > CAP_B) nitems = CAP_B;

    for (int item = gwave; item < nitems; item += nwaves) {
        int pix = listB[item];
        int b = pix >> 12, h = (pix >> 6) & 63, w = pix & 63;
        const float* zp = z + (size_t)b * BSTRIDE + h * HW + w;

        float za = zp[(size_t)lane * PLANE];
        float zb = zp[(size_t)(lane + 64) * PLANE];
        zsh[wv][lane] = za;                    // wave-internal: in-order LDS
        zsh[wv][lane + 64] = zb;
        const float* zr = zsh[wv];

        float Apair;
        {
#pragma clang fp contract(off)
            float r0,r1,r2,r3,r4,r5,r6,r7;
            r0 = zr[0]*zr[0]; r1 = zr[1]*zr[1]; r2 = zr[2]*zr[2]; r3 = zr[3]*zr[3];
            r4 = zr[4]*zr[4]; r5 = zr[5]*zr[5]; r6 = zr[6]*zr[6]; r7 = zr[7]*zr[7];
#pragma unroll
            for (int i = 8; i < DDIM; i += 8) {
                r0 += zr[i+0]*zr[i+0]; r1 += zr[i+1]*zr[i+1];
                r2 += zr[i+2]*zr[i+2]; r3 += zr[i+3]*zr[i+3];
                r4 += zr[i+4]*zr[i+4]; r5 += zr[i+5]*zr[i+5];
                r6 += zr[i+6]*zr[i+6]; r7 += zr[i+7]*zr[i+7];
            }
            Apair = ((r0+r1)+(r2+r3)) + ((r4+r5)+(r6+r7));
        }

        // fp32 prefilter: lane owns codes k = g*64+lane, g=0..15
        float dot[16];
#pragma unroll
        for (int g = 0; g < 16; ++g) dot[g] = 0.0f;
        for (int i = 0; i < 32; ++i) {
            f32x4 zv = *(const f32x4*)(zr + i * 4);   // broadcast LDS read
#pragma unroll
            for (int g = 0; g < 16; ++g) {
                const f32x4 cv = *(const f32x4*)(cb + (size_t)(g * 64 + lane) * DDIM + i * 4);
                dot[g] = __builtin_fmaf(zv[0], cv[0],
                         __builtin_fmaf(zv[1], cv[1],
                         __builtin_fmaf(zv[2], cv[2],
                         __builtin_fmaf(zv[3], cv[3], dot[g]))));
            }
        }
        float est[16]; float smin = 3.4e38f;
#pragma unroll
        for (int g = 0; g < 16; ++g) {
            est[g] = Bsum[g * 64 + lane] - 2.0f * dot[g];
            smin = fminf(smin, est[g]);
        }
        for (int off = 32; off; off >>= 1)
            smin = fminf(smin, __shfl_xor(smin, off, 64));

        float bd = 3.4e38f; int bk = 1 << 30;
#pragma unroll 1
        for (int g = 0; g < 16; ++g) {
            if (est[g] <= smin + BAND) {
                int k = g * 64 + lane;
                const float* c = cb + (size_t)k * DDIM;
                double p = 0.0;
                for (int i = 0; i < DDIM; ++i)
                    p = fma((double)zr[i], (double)c[i], p);
                float Dk;
                {
#pragma clang fp contract(off)
                    float t1 = Apair + Bsum[k];
                    float u = (float)(2.0 * p);
                    Dk = t1 - u;
                }
                if (Dk < bd || (Dk == bd && k < bk)) { bd = Dk; bk = k; }
            }
        }
        for (int off = 32; off; off >>= 1) {
            float od = __shfl_xor(bd, off, 64);
            int   ok = __shfl_xor(bk, off, 64);
            bool better = (od < bd) || (od == bd && ok < bk);
            bd = better ? od : bd;
            bk = better ? ok : bk;
        }

        const float* cw = cb + (size_t)bk * DDIM;
        float* op = out + (size_t)b * BSTRIDE + h * HW + w;
        op[(size_t)lane * PLANE] = cw[lane];
        op[(size_t)(lane + 64) * PLANE] = cw[lane + 64];
    }
}

// ---------------------------------------------------------------------------
extern "C" void kernel_launch(void* const* d_in, const int* in_sizes, int n_in,
                              void* d_out, int out_size, void* d_ws, size_t ws_size,
                              hipStream_t stream) {
    const float* z  = (const float*)d_in[0];
    const float* cb = (const float*)d_in[1];
    float* out = (float*)d_out;

    // ws: Bsum 4K | Bs1024 4K | cnts 4K | bs16 256K | listA 512K | listB 32K
    float* Bsum   = (float*)d_ws;
    float* Bs1024 = (float*)((char*)d_ws + 4096);
    int*   cnts   = (int*)((char*)d_ws + 8192);
    _Float16* bs16 = (_Float16*)((char*)d_ws + 12288);
    int2*  listA  = (int2*)((char*)d_ws + 12288 + 262144);
    int*   listB  = (int*)((char*)d_ws + 12288 + 262144 + 524288);
    int* cntA = cnts; int* cntB = cnts + 1;

    prep_kernel<<<68, 256, 0, stream>>>(cb, Bsum, Bs1024, bs16, cnts);
    phase1_mfma<<<NPIX / 128, 256, 0, stream>>>(z, cb, bs16, Bs1024, out,
                                                cntA, listA, cntB, listB);
    phase3a_kernel<<<1024, 256, 0, stream>>>(z, cb, Bsum, out, cntA, listA);
    phase3b_kernel<<<128, 256, 0, stream>>>(z, cb, Bsum, out, cntB, listB);
}